// Round 6
// baseline (157.264 us; speedup 1.0000x reference)
//
#include <hip/hip_runtime.h>
#include <math.h>

#define B 4
#define P 32768
#define C 8
#define F 32
#define D 64
#define H 64

typedef __attribute__((ext_vector_type(8))) short bf16x8;
typedef __attribute__((ext_vector_type(4))) float f32x4;

__device__ __forceinline__ short f2bf(float f) {
    union { float f; unsigned u; } v; v.f = f;
    unsigned r = (v.u + 0x7FFFu + ((v.u >> 16) & 1u)) >> 16;   // RNE
    return (short)r;
}

// packed f32x2 -> bf16x2 (RNE) in one VALU op
__device__ __forceinline__ unsigned cvt_pk_bf16(float lo, float hi) {
    unsigned r;
    asm("v_cvt_pk_bf16_f32 %0, %1, %2" : "=v"(r) : "v"(lo), "v"(hi));
    return r;
}

// async global->LDS, 16B per lane. LDS dest = wave-uniform base + lane*16;
// global src = per-lane address (guide §5).
__device__ __forceinline__ void gload_lds16(const void* g, void* s) {
    __builtin_amdgcn_global_load_lds(
        (const __attribute__((address_space(1))) unsigned*)g,
        (__attribute__((address_space(3))) unsigned*)s, 16, 0, 0);
}

// ---------------------------------------------------------------------------
// repack_relu: D-form accumulators -> B-frag pair, entirely in registers.
// Input (per lane (q,l16)): v[a][r] = act[point=l16, n = 16a + 4q + r].
// Output: f0/f1 = B-frags for the next MFMA: lane holds point l16's
// k = 8q+j (f0: k<32) and k = 32+8q+j (f1).
// Algorithm (verified lane-by-lane for all 4 quads):
//   pack pairs (cvt_pk) -> u[a][p]
//   step1 (xor16): consolidate both sources of each s1-pair, split by a-half
//   step2 (conditional xor48): lanes with q0!=q1 swap whole frag sets
// Replaces the LDS write->lgkm-wait->b128-read transform (~250cy + 128 bank-
// conflict cycles per stage) with ~40 register ops.
// ---------------------------------------------------------------------------
__device__ __forceinline__ void repack_relu(const f32x4* v, int lane,
                                            bf16x8& f0, bf16x8& f1)
{
    unsigned u00 = cvt_pk_bf16(fmaxf(v[0][0], 0.f), fmaxf(v[0][1], 0.f));
    unsigned u01 = cvt_pk_bf16(fmaxf(v[0][2], 0.f), fmaxf(v[0][3], 0.f));
    unsigned u10 = cvt_pk_bf16(fmaxf(v[1][0], 0.f), fmaxf(v[1][1], 0.f));
    unsigned u11 = cvt_pk_bf16(fmaxf(v[1][2], 0.f), fmaxf(v[1][3], 0.f));
    unsigned u20 = cvt_pk_bf16(fmaxf(v[2][0], 0.f), fmaxf(v[2][1], 0.f));
    unsigned u21 = cvt_pk_bf16(fmaxf(v[2][2], 0.f), fmaxf(v[2][3], 0.f));
    unsigned u30 = cvt_pk_bf16(fmaxf(v[3][0], 0.f), fmaxf(v[3][1], 0.f));
    unsigned u31 = cvt_pk_bf16(fmaxf(v[3][2], 0.f), fmaxf(v[3][3], 0.f));
    const bool x0 = (lane & 16) != 0;
    // send the a-half we don't keep (keep a in {q0, q0+2})
    unsigned s0 = x0 ? u00 : u10, s1 = x0 ? u01 : u11;
    unsigned s2 = x0 ? u20 : u30, s3 = x0 ? u21 : u31;
    unsigned r0 = (unsigned)__shfl_xor((int)s0, 16);
    unsigned r1 = (unsigned)__shfl_xor((int)s1, 16);
    unsigned r2 = (unsigned)__shfl_xor((int)s2, 16);
    unsigned r3 = (unsigned)__shfl_xor((int)s3, 16);
    // order blocks by source parity s0: B0 = s0-even block, B1 = s0-odd
    unsigned o0 = x0 ? r0  : u00, o1 = x0 ? r1  : u01;   // B0[0..1]
    unsigned o4 = x0 ? r2  : u20, o5 = x0 ? r3  : u21;   // B0[2..3]
    unsigned o2 = x0 ? u10 : r0,  o3 = x0 ? u11 : r1;    // B1[0..1]
    unsigned o6 = x0 ? u30 : r2,  o7 = x0 ? u31 : r3;    // B1[2..3]
    // step2: lanes with q0 != q1 swap entire sets with their xor48 partner
    const bool sw = (((lane >> 4) ^ (lane >> 5)) & 1) != 0;
    unsigned t;
    t = (unsigned)__shfl_xor((int)o0, 48); o0 = sw ? t : o0;
    t = (unsigned)__shfl_xor((int)o1, 48); o1 = sw ? t : o1;
    t = (unsigned)__shfl_xor((int)o2, 48); o2 = sw ? t : o2;
    t = (unsigned)__shfl_xor((int)o3, 48); o3 = sw ? t : o3;
    t = (unsigned)__shfl_xor((int)o4, 48); o4 = sw ? t : o4;
    t = (unsigned)__shfl_xor((int)o5, 48); o5 = sw ? t : o5;
    t = (unsigned)__shfl_xor((int)o6, 48); o6 = sw ? t : o6;
    t = (unsigned)__shfl_xor((int)o7, 48); o7 = sw ? t : o7;
    union { unsigned u[4]; bf16x8 v8; } A, Bv;
    A.u[0] = o0; A.u[1] = o1; A.u[2] = o2; A.u[3] = o3;
    Bv.u[0] = o4; Bv.u[1] = o5; Bv.u[2] = o6; Bv.u[3] = o7;
    f0 = A.v8; f1 = Bv.v8;
}

// ---------------------------------------------------------------------------
// Merged setup kernel. r6 CHANGE: all n-major storage now uses NATURAL rows
// (the column permutation is gone — the swapped-operand main kernel consumes
// weights as A-operands with natural n rows). Bxt keeps the XOR swizzle
// short_idx ^= (row&7)<<3 for conflict-free ds_read_b128 from the LDS-staged
// copy (rule #21: baked into the global source; global_load_lds is linear).
// ---------------------------------------------------------------------------
__global__ __launch_bounds__(256)
void setup_kernel(const float* __restrict__ z,
                  const float* __restrict__ W_dir,
                  const float* __restrict__ W0,
                  const float* __restrict__ b0,
                  const float* __restrict__ Wa,
                  const float* __restrict__ Wb,
                  short* __restrict__ Bxt,
                  short* __restrict__ Wat,
                  short* __restrict__ Wbt)
{
    if (blockIdx.x >= 32) {
        int idx = (blockIdx.x - 32) * 256 + threadIdx.x;  // < 5*64*64
        int i = idx >> 12, r = idx & 4095, k = r >> 6, n = r & 63;
        int o = (i << 12) + (n << 6) + k;                 // natural n-major
        Wat[o] = f2bf(Wa[idx]);
        Wbt[o] = f2bf(Wb[idx]);
        return;
    }
    const int bc = blockIdx.x;
    const int t  = threadIdx.x & 63;     // output column n (natural row now)
    const int g  = threadIdx.x >> 6;     // f-group 0..3
    const float* zb = z + (size_t)bc * F * D;

    __shared__ float zl[F][D];       // 8 KB
    __shared__ float wdir[D][D];     // 16 KB
    __shared__ float w0m[D][H];      // 16 KB (W0 rows 1..64)
    __shared__ float zp[4][D];       // 1 KB
    __shared__ float zq[4][D];       // 1 KB

    for (int i = threadIdx.x; i < F * D; i += 256) zl[i >> 6][i & 63] = zb[i];
    for (int i = threadIdx.x; i < D * D; i += 256) wdir[i >> 6][i & 63] = W_dir[i];
    for (int i = threadIdx.x; i < D * H; i += 256) w0m[i >> 6][i & 63] = W0[H + i];
    __syncthreads();

    const int sw = (t & 7) << 3;                      // bank swizzle (shorts)
    short* brow = Bxt + ((size_t)bc * 64 + t) * 64;   // natural row = n

    float zi = 0.f;
    for (int f = g * 8; f < g * 8 + 8; ++f) {
        float z0 = 0, z1 = 0, z2 = 0, z3 = 0;
        float a0 = 0, a1 = 0, a2 = 0, a3 = 0;
#pragma unroll
        for (int d = 0; d < D; d += 4) {
            float4 z4 = *(const float4*)&zl[f][d];    // broadcast b128
            z0 += z4.x * wdir[d + 0][t];
            z1 += z4.y * wdir[d + 1][t];
            z2 += z4.z * wdir[d + 2][t];
            z3 += z4.w * wdir[d + 3][t];
            a0 += z4.x * w0m[d + 0][t];
            a1 += z4.y * w0m[d + 1][t];
            a2 += z4.z * w0m[d + 2][t];
            a3 += z4.w * w0m[d + 3][t];
        }
        zi += zl[f][t] * ((z0 + z1) + (z2 + z3));
        brow[f ^ sw] = f2bf((a0 + a1) + (a2 + a3));   // ZW row f, col t
    }
    zp[g][t] = zi;
    __syncthreads();
    if (g == 0) {
        float zall = zp[0][t] + zp[1][t] + zp[2][t] + zp[3][t];
        zp[0][t] = zall;                              // full z_inv[t]
    }
    __syncthreads();
    // zc partials: each g-group covers 16 e's
    {
        float zcp = 0.f;
        for (int e = g * 16; e < g * 16 + 16; ++e)
            zcp += zp[0][e] * W0[(65 + e) * H + t];
        zq[g][t] = zcp;
    }
    __syncthreads();
    if (g == 0) {
        brow[32 ^ sw] = f2bf(W0[t]);                  // multiplies s2
        float zc = b0[t] + zq[0][t] + zq[1][t] + zq[2][t] + zq[3][t];
        brow[33 ^ sw] = f2bf(zc);                     // multiplies 1
    } else if (g == 1) {
        for (int k = 34; k < 64; ++k) brow[k ^ sw] = 0;
    }
}

// ---------------------------------------------------------------------------
// Main. r6 KEY CHANGE: swapped-operand MFMAs — every GEMM computes
// mfma(A=W^T frag, B=act frag) so the D-layout keeps the POINT on lane&15
// permanently. The inter-layer C->A transform collapses from a 16-wide LDS
// transpose (write -> lgkm wait -> b128 read, 12 per wave, 128 bank-conflict
// cycles each) to a 4-way quad-local register shuffle (repack_relu).
// No LDS transform buffers at all; block LDS = 16 KB Bxt dbuf only.
// Layer-0 weights (Wa0,Wb0) hoisted as A-frags; biases/Wout loaded in D-form
// (float4 at n-offset 16nt+4q). Head: per-lane dot + xor16/xor32 reduce.
// launch_bounds(256,2) — NEVER higher min-waves on this kernel (r1/r4 spills).
// ---------------------------------------------------------------------------
__global__ __launch_bounds__(256, 2)
void main_kernel(const float* __restrict__ p,      // (B,P,3)
                 const float* __restrict__ pos,    // (B,3)
                 const float* __restrict__ W_feat, // (3,F)
                 const short* __restrict__ Bxt,    // (B,C,64n,64k) bf16 (swz)
                 const short* __restrict__ Wat,    // (5,64n,64k) natural
                 const short* __restrict__ Wbt,    // (5,64n,64k) natural
                 const float* __restrict__ ba,     // (5,H)
                 const float* __restrict__ bb,     // (5,H)
                 const float* __restrict__ Wout,   // (H,1)
                 const float* __restrict__ bout,   // (1,)
                 float* __restrict__ out)          // (B,P)
{
    const int wave = threadIdx.x >> 6;
    const int lane = threadIdx.x & 63;
    const int quad = lane >> 4;
    const int l16  = lane & 15;
    const int b    = blockIdx.y;
    const int base = blockIdx.x * 128 + wave * 32;

    __shared__ __attribute__((aligned(16))) short bxlds[2][4096]; // 16 KB dbuf

    const short* bxg = Bxt + (size_t)b * C * 4096;

    // ---- issue staging of c=0 immediately (lands under the preamble)
    {
        const short* src = bxg + (wave * 2) * 512 + lane * 8;
        gload_lds16(src,       &bxlds[0][(wave * 2) * 512]);
        gload_lds16(src + 512, &bxlds[0][(wave * 2 + 1) * 512]);
    }

    // ---- point features -> B-frags for both m-tiles (content unchanged:
    //      lane (q,l16) holds point l16's k = 8q+j — valid as B operand)
    bf16x8 a0[2], a1[2];
#pragma unroll
    for (int m = 0; m < 2; ++m) {
        const float* pp = p + ((size_t)b * P + base + m * 16 + l16) * 3;
        float px = pp[0] - pos[b * 3 + 0];
        float py = pp[1] - pos[b * 3 + 1];
        float pz = pp[2] - pos[b * 3 + 2];
        float nrm = sqrtf(px * px + py * py + pz * pz);
        if (nrm > 0.5f) { float s = 0.5f / nrm; px *= s; py *= s; pz *= s; }
        float av[8];
        float s2 = 0.f;
#pragma unroll
        for (int j = 0; j < 8; ++j) {
            int k = quad * 8 + j;
            av[j] = px * W_feat[k] + py * W_feat[F + k] + pz * W_feat[2 * F + k];
            s2 += av[j] * av[j];
        }
        s2 += __shfl_xor(s2, 16);
        s2 += __shfl_xor(s2, 32);
        union { bf16x8 v; unsigned u[4]; } ua;
#pragma unroll
        for (int j = 0; j < 4; ++j) ua.u[j] = cvt_pk_bf16(av[2 * j], av[2 * j + 1]);
        a0[m] = ua.v;
        union { bf16x8 v; unsigned u[4]; } ub;
#pragma unroll
        for (int j = 0; j < 4; ++j) ub.u[j] = 0;
        if (quad == 0) ub.u[0] = cvt_pk_bf16(s2, 1.0f);
        a1[m] = ub.v;
    }

    f32x4 pooled[2][4];
#pragma unroll
    for (int m = 0; m < 2; ++m)
#pragma unroll
        for (int nt = 0; nt < 4; ++nt)
            pooled[m][nt] = (f32x4){-1e30f, -1e30f, -1e30f, -1e30f};

    // ---- biases in D-form: n = 16nt + 4q + r  ->  float4 at +16nt+4q
    float4 ba0v[4], bb0v[4];
#pragma unroll
    for (int nt = 0; nt < 4; ++nt) {
        ba0v[nt] = *(const float4*)(ba + nt * 16 + 4 * quad);
        bb0v[nt] = *(const float4*)(bb + nt * 16 + 4 * quad);
    }

    // ---- hoist layer-0 weight A-frags (c-invariant; 64 VGPRs)
    bf16x8 wa0f[4][2], wb0f[4][2];
#pragma unroll
    for (int nt = 0; nt < 4; ++nt) {
        wa0f[nt][0] = *(const bf16x8*)(Wat + (nt * 16 + l16) * 64 + quad * 8);
        wa0f[nt][1] = *(const bf16x8*)(Wat + (nt * 16 + l16) * 64 + 32 + quad * 8);
        wb0f[nt][0] = *(const bf16x8*)(Wbt + (nt * 16 + l16) * 64 + quad * 8);
        wb0f[nt][1] = *(const bf16x8*)(Wbt + (nt * 16 + l16) * 64 + 32 + quad * 8);
    }

    __syncthreads();   // drains vmcnt: bxlds[0] is published

    // =============== c-loop: 1 channel per iter, 2 m-chains =================
#pragma unroll 1
    for (int c = 0; c < C; ++c) {
        // ---- issue staging for c+1 (lands during S1-S3, sealed by barrier)
        if (c + 1 < C) {
            const short* src = bxg + (size_t)(c + 1) * 4096 + (wave * 2) * 512 + lane * 8;
            gload_lds16(src,       &bxlds[(c + 1) & 1][(wave * 2) * 512]);
            gload_lds16(src + 512, &bxlds[(c + 1) & 1][(wave * 2 + 1) * 512]);
        }
        const short* bxs = &bxlds[c & 1][0];

        // ---- S1: x[n, point] = mfma(Bxt^T frag, point-feat frag)
        f32x4 x[2][4];
#pragma unroll
        for (int nt = 0; nt < 4; ++nt) {
            const int row = nt * 16 + l16;
            const int sw  = (row & 7) << 3;
            bf16x8 b0f = *(const bf16x8*)(bxs + row * 64 + ((quad * 8) ^ sw));
            bf16x8 b1f = *(const bf16x8*)(bxs + row * 64 + ((32 + quad * 8) ^ sw));
#pragma unroll
            for (int m = 0; m < 2; ++m) {
                f32x4 acc = (f32x4){0.f, 0.f, 0.f, 0.f};
                acc = __builtin_amdgcn_mfma_f32_16x16x32_bf16(b0f, a0[m], acc, 0, 0, 0);
                acc = __builtin_amdgcn_mfma_f32_16x16x32_bf16(b1f, a1[m], acc, 0, 0, 0);
                x[m][nt] = acc;
            }
        }

        // ---- repack relu(x) -> B-frags (register-only transform)
        bf16x8 xf0[2], xf1[2];
#pragma unroll
        for (int m = 0; m < 2; ++m) repack_relu(x[m], lane, xf0[m], xf1[m]);

        // ---- S2: h = relu(x) @ Wa0 + ba0   (D-form acc init from ba0v)
        f32x4 h[2][4];
#pragma unroll
        for (int nt = 0; nt < 4; ++nt) {
#pragma unroll
            for (int m = 0; m < 2; ++m) {
                f32x4 acc = (f32x4){ba0v[nt].x, ba0v[nt].y, ba0v[nt].z, ba0v[nt].w};
                acc = __builtin_amdgcn_mfma_f32_16x16x32_bf16(wa0f[nt][0], xf0[m], acc, 0, 0, 0);
                acc = __builtin_amdgcn_mfma_f32_16x16x32_bf16(wa0f[nt][1], xf1[m], acc, 0, 0, 0);
                h[m][nt] = acc;
            }
        }

        // ---- repack relu(h)
        bf16x8 hf0[2], hf1[2];
#pragma unroll
        for (int m = 0; m < 2; ++m) repack_relu(h[m], lane, hf0[m], hf1[m]);

        // ---- S3: x + bb0 + relu(h) @ Wb0 ; max-pool over c
#pragma unroll
        for (int nt = 0; nt < 4; ++nt) {
#pragma unroll
            for (int m = 0; m < 2; ++m) {
                f32x4 acc = x[m][nt];
                acc[0] += bb0v[nt].x; acc[1] += bb0v[nt].y;
                acc[2] += bb0v[nt].z; acc[3] += bb0v[nt].w;
                acc = __builtin_amdgcn_mfma_f32_16x16x32_bf16(wb0f[nt][0], hf0[m], acc, 0, 0, 0);
                acc = __builtin_amdgcn_mfma_f32_16x16x32_bf16(wb0f[nt][1], hf1[m], acc, 0, 0, 0);
#pragma unroll
                for (int r = 0; r < 4; ++r)
                    pooled[m][nt][r] = fmaxf(pooled[m][nt][r], acc[r]);
            }
        }

        __syncthreads();   // publishes staged buffer; seals dbuf epochs
    }

    // =============== residual blocks 1..4 (2 chains: m-tiles) ===============
#pragma unroll
    for (int i = 1; i < 5; ++i) {
        const short* wa = Wat + i * 4096;
        const short* wb = Wbt + i * 4096;
        float4 bai[4], bbi[4];
#pragma unroll
        for (int nt = 0; nt < 4; ++nt) {
            bai[nt] = *(const float4*)(ba + i * H + nt * 16 + 4 * quad);
            bbi[nt] = *(const float4*)(bb + i * H + nt * 16 + 4 * quad);
        }

        bf16x8 pf0[2], pf1[2];
#pragma unroll
        for (int m = 0; m < 2; ++m) repack_relu(pooled[m], lane, pf0[m], pf1[m]);

        f32x4 h[2][4];
#pragma unroll
        for (int nt = 0; nt < 4; ++nt) {
            bf16x8 w0f = *(const bf16x8*)(wa + (nt * 16 + l16) * 64 + quad * 8);
            bf16x8 w1f = *(const bf16x8*)(wa + (nt * 16 + l16) * 64 + 32 + quad * 8);
#pragma unroll
            for (int m = 0; m < 2; ++m) {
                f32x4 acc = (f32x4){bai[nt].x, bai[nt].y, bai[nt].z, bai[nt].w};
                acc = __builtin_amdgcn_mfma_f32_16x16x32_bf16(w0f, pf0[m], acc, 0, 0, 0);
                acc = __builtin_amdgcn_mfma_f32_16x16x32_bf16(w1f, pf1[m], acc, 0, 0, 0);
                h[m][nt] = acc;
            }
        }

        bf16x8 hf0[2], hf1[2];
#pragma unroll
        for (int m = 0; m < 2; ++m) repack_relu(h[m], lane, hf0[m], hf1[m]);

#pragma unroll
        for (int nt = 0; nt < 4; ++nt) {
            bf16x8 w0f = *(const bf16x8*)(wb + (nt * 16 + l16) * 64 + quad * 8);
            bf16x8 w1f = *(const bf16x8*)(wb + (nt * 16 + l16) * 64 + 32 + quad * 8);
#pragma unroll
            for (int m = 0; m < 2; ++m) {
                f32x4 acc = pooled[m][nt];
                acc[0] += bbi[nt].x; acc[1] += bbi[nt].y;
                acc[2] += bbi[nt].z; acc[3] += bbi[nt].w;
                acc = __builtin_amdgcn_mfma_f32_16x16x32_bf16(w0f, hf0[m], acc, 0, 0, 0);
                acc = __builtin_amdgcn_mfma_f32_16x16x32_bf16(w1f, hf1[m], acc, 0, 0, 0);
                pooled[m][nt] = acc;
            }
        }
    }

    // =============== head: per-lane dot + cross-quad reduce =================
    const float bo = bout[0];
    float4 wo4[4];
#pragma unroll
    for (int nt = 0; nt < 4; ++nt)
        wo4[nt] = *(const float4*)(Wout + nt * 16 + 4 * quad);
#pragma unroll
    for (int m = 0; m < 2; ++m) {
        float s = 0.f;
#pragma unroll
        for (int nt = 0; nt < 4; ++nt) {
            s += fmaxf(pooled[m][nt][0], 0.f) * wo4[nt].x
               + fmaxf(pooled[m][nt][1], 0.f) * wo4[nt].y
               + fmaxf(pooled[m][nt][2], 0.f) * wo4[nt].z
               + fmaxf(pooled[m][nt][3], 0.f) * wo4[nt].w;
        }
        s += __shfl_xor(s, 16);
        s += __shfl_xor(s, 32);
        if (lane < 16)
            out[(size_t)b * P + base + m * 16 + l16] = s + bo;
    }
}

extern "C" void kernel_launch(void* const* d_in, const int* in_sizes, int n_in,
                              void* d_out, int out_size, void* d_ws, size_t ws_size,
                              hipStream_t stream) {
    const float* z      = (const float*)d_in[0];
    const float* pos    = (const float*)d_in[1];
    const float* p      = (const float*)d_in[2];
    const float* W_feat = (const float*)d_in[3];
    const float* W_dir  = (const float*)d_in[4];
    const float* W0     = (const float*)d_in[5];
    const float* b0     = (const float*)d_in[6];
    const float* Wa     = (const float*)d_in[7];
    const float* ba     = (const float*)d_in[8];
    const float* Wb     = (const float*)d_in[9];
    const float* bb     = (const float*)d_in[10];
    const float* Wout   = (const float*)d_in[11];
    const float* bout   = (const float*)d_in[12];
    float* out = (float*)d_out;

    short* wsS = (short*)d_ws;
    short* Bxt = wsS;                    // B*C*64*64 shorts
    short* Wat = wsS + 32 * 4096;        // 5*4096
    short* Wbt = Wat + 5 * 4096;         // 5*4096

    setup_kernel<<<112, 256, 0, stream>>>(z, W_dir, W0, b0, Wa, Wb, Bxt, Wat, Wbt);

    dim3 grid(P / 128, B);
    main_kernel<<<grid, 256, 0, stream>>>(p, pos, W_feat, Bxt, Wat, Wbt,
                                          ba, bb, Wout, bout, out);
}

// Round 7
// 145.727 us; speedup vs baseline: 1.0792x; 1.0792x over previous
//
#include <hip/hip_runtime.h>
#include <math.h>

#define B 4
#define P 32768
#define C 8
#define F 32
#define D 64
#define H 64

typedef __attribute__((ext_vector_type(8))) short bf16x8;
typedef __attribute__((ext_vector_type(4))) float f32x4;

__device__ __forceinline__ short f2bf(float f) {
    union { float f; unsigned u; } v; v.f = f;
    unsigned r = (v.u + 0x7FFFu + ((v.u >> 16) & 1u)) >> 16;   // RNE
    return (short)r;
}

// packed f32x2 -> bf16x2 (RNE) in one VALU op
__device__ __forceinline__ unsigned cvt_pk_bf16(float lo, float hi) {
    unsigned r;
    asm("v_cvt_pk_bf16_f32 %0, %1, %2" : "=v"(r) : "v"(lo), "v"(hi));
    return r;
}

// async global->LDS, 16B per lane. LDS dest = wave-uniform base + lane*16;
// global src = per-lane address (guide §5).
__device__ __forceinline__ void gload_lds16(const void* g, void* s) {
    __builtin_amdgcn_global_load_lds(
        (const __attribute__((address_space(1))) unsigned*)g,
        (__attribute__((address_space(3))) unsigned*)s, 16, 0, 0);
}

// ---------------------------------------------------------------------------
// repack_relu (r7): D-form accumulators -> B-frag pair ENTIRELY IN-LANE.
// k-axis permutation trick: MFMA contracts a shared k-index whose meaning is
// arbitrary as long as A and B agree. With pi(32f+8q+j) = 16(2f+(j>>2)) +
// 4q + (j&3), lane (q,l16)'s D-form values {n = 16nt+4q+r} ARE its two
// B-frags in register order:
//   f0 = [nt0 r0..r3, nt1 r0..r3], f1 = [nt2 r0..r3, nt3 r0..r3]
// Weights absorb pi at setup (storage row kslot holds W[pi(kslot)][n_out]).
// Cost: 16 fmax + 8 cvt_pk. No shuffles (r6's 12 ds_bpermute killed it),
// no LDS round-trip (r3's 250cy+conflicts per stage).
// ---------------------------------------------------------------------------
__device__ __forceinline__ void repack_relu(const f32x4* v, bf16x8& f0, bf16x8& f1)
{
    union { unsigned u[4]; bf16x8 v8; } A, Bv;
    A.u[0]  = cvt_pk_bf16(fmaxf(v[0][0], 0.f), fmaxf(v[0][1], 0.f));
    A.u[1]  = cvt_pk_bf16(fmaxf(v[0][2], 0.f), fmaxf(v[0][3], 0.f));
    A.u[2]  = cvt_pk_bf16(fmaxf(v[1][0], 0.f), fmaxf(v[1][1], 0.f));
    A.u[3]  = cvt_pk_bf16(fmaxf(v[1][2], 0.f), fmaxf(v[1][3], 0.f));
    Bv.u[0] = cvt_pk_bf16(fmaxf(v[2][0], 0.f), fmaxf(v[2][1], 0.f));
    Bv.u[1] = cvt_pk_bf16(fmaxf(v[2][2], 0.f), fmaxf(v[2][3], 0.f));
    Bv.u[2] = cvt_pk_bf16(fmaxf(v[3][0], 0.f), fmaxf(v[3][1], 0.f));
    Bv.u[3] = cvt_pk_bf16(fmaxf(v[3][2], 0.f), fmaxf(v[3][3], 0.f));
    f0 = A.v8; f1 = Bv.v8;
}

// ---------------------------------------------------------------------------
// Merged setup kernel. r7 CHANGE: Wa/Wb storage rows are k-PERMUTED by pi
// (storage[n_out][kslot] = W[pi(kslot)][n_out]) so main's activation repack
// is in-lane. Bxt: natural n rows, identity k (feature axis), XOR swizzle
// short_idx ^= (row&7)<<3 for conflict-free staged ds_read_b128 (rule #21).
// ---------------------------------------------------------------------------
__global__ __launch_bounds__(256)
void setup_kernel(const float* __restrict__ z,
                  const float* __restrict__ W_dir,
                  const float* __restrict__ W0,
                  const float* __restrict__ b0,
                  const float* __restrict__ Wa,
                  const float* __restrict__ Wb,
                  short* __restrict__ Bxt,
                  short* __restrict__ Wat,
                  short* __restrict__ Wbt)
{
    if (blockIdx.x >= 32) {
        int idx = (blockIdx.x - 32) * 256 + threadIdx.x;  // < 5*64*64
        int i = idx >> 12, r = idx & 4095, ks = r >> 6, n = r & 63;
        int f = ks >> 5, q = (ks >> 3) & 3, j = ks & 7;
        int nin = 16 * (2 * f + (j >> 2)) + 4 * q + (j & 3);   // pi(kslot)
        int o   = (i << 12) + (n << 6) + ks;                   // [n_out][kslot]
        int src = (i << 12) + (nin << 6) + n;                  // W[i][nin][n]
        Wat[o] = f2bf(Wa[src]);
        Wbt[o] = f2bf(Wb[src]);
        return;
    }
    const int bc = blockIdx.x;
    const int t  = threadIdx.x & 63;     // output column n (natural row)
    const int g  = threadIdx.x >> 6;     // f-group 0..3
    const float* zb = z + (size_t)bc * F * D;

    __shared__ float zl[F][D];       // 8 KB
    __shared__ float wdir[D][D];     // 16 KB
    __shared__ float w0m[D][H];      // 16 KB (W0 rows 1..64)
    __shared__ float zp[4][D];       // 1 KB
    __shared__ float zq[4][D];       // 1 KB

    for (int i = threadIdx.x; i < F * D; i += 256) zl[i >> 6][i & 63] = zb[i];
    for (int i = threadIdx.x; i < D * D; i += 256) wdir[i >> 6][i & 63] = W_dir[i];
    for (int i = threadIdx.x; i < D * H; i += 256) w0m[i >> 6][i & 63] = W0[H + i];
    __syncthreads();

    const int sw = (t & 7) << 3;                      // bank swizzle (shorts)
    short* brow = Bxt + ((size_t)bc * 64 + t) * 64;   // natural row = n

    float zi = 0.f;
    for (int f = g * 8; f < g * 8 + 8; ++f) {
        float z0 = 0, z1 = 0, z2 = 0, z3 = 0;
        float a0 = 0, a1 = 0, a2 = 0, a3 = 0;
#pragma unroll
        for (int d = 0; d < D; d += 4) {
            float4 z4 = *(const float4*)&zl[f][d];    // broadcast b128
            z0 += z4.x * wdir[d + 0][t];
            z1 += z4.y * wdir[d + 1][t];
            z2 += z4.z * wdir[d + 2][t];
            z3 += z4.w * wdir[d + 3][t];
            a0 += z4.x * w0m[d + 0][t];
            a1 += z4.y * w0m[d + 1][t];
            a2 += z4.z * w0m[d + 2][t];
            a3 += z4.w * w0m[d + 3][t];
        }
        zi += zl[f][t] * ((z0 + z1) + (z2 + z3));
        brow[f ^ sw] = f2bf((a0 + a1) + (a2 + a3));   // ZW row f, col t
    }
    zp[g][t] = zi;
    __syncthreads();
    if (g == 0) {
        float zall = zp[0][t] + zp[1][t] + zp[2][t] + zp[3][t];
        zp[0][t] = zall;                              // full z_inv[t]
    }
    __syncthreads();
    // zc partials: each g-group covers 16 e's
    {
        float zcp = 0.f;
        for (int e = g * 16; e < g * 16 + 16; ++e)
            zcp += zp[0][e] * W0[(65 + e) * H + t];
        zq[g][t] = zcp;
    }
    __syncthreads();
    if (g == 0) {
        brow[32 ^ sw] = f2bf(W0[t]);                  // multiplies s2
        float zc = b0[t] + zq[0][t] + zq[1][t] + zq[2][t] + zq[3][t];
        brow[33 ^ sw] = f2bf(zc);                     // multiplies 1
    } else if (g == 1) {
        for (int k = 34; k < 64; ++k) brow[k ^ sw] = 0;
    }
}

// ---------------------------------------------------------------------------
// Main. r7: swapped-operand MFMAs (verified r6) + pi-permuted k-axis so the
// inter-layer transform is a pure in-lane repack (8 cvt_pk + 16 fmax; no
// shuffles, no LDS). Weight A-frags read the pi-permuted storage with the
// SAME pattern as r6 (kslot-contiguous). S1's k axis (features) is identity.
// Block LDS = 16 KB Bxt dbuf only.
// launch_bounds(256,2) — NEVER higher min-waves (r1/r4 spill lessons).
// ---------------------------------------------------------------------------
__global__ __launch_bounds__(256, 2)
void main_kernel(const float* __restrict__ p,      // (B,P,3)
                 const float* __restrict__ pos,    // (B,3)
                 const float* __restrict__ W_feat, // (3,F)
                 const short* __restrict__ Bxt,    // (B,C,64n,64k) bf16 (swz)
                 const short* __restrict__ Wat,    // (5,64n,64kslot) pi-perm
                 const short* __restrict__ Wbt,    // (5,64n,64kslot) pi-perm
                 const float* __restrict__ ba,     // (5,H)
                 const float* __restrict__ bb,     // (5,H)
                 const float* __restrict__ Wout,   // (H,1)
                 const float* __restrict__ bout,   // (1,)
                 float* __restrict__ out)          // (B,P)
{
    const int wave = threadIdx.x >> 6;
    const int lane = threadIdx.x & 63;
    const int quad = lane >> 4;
    const int l16  = lane & 15;
    const int b    = blockIdx.y;
    const int base = blockIdx.x * 128 + wave * 32;

    __shared__ __attribute__((aligned(16))) short bxlds[2][4096]; // 16 KB dbuf

    const short* bxg = Bxt + (size_t)b * C * 4096;

    // ---- issue staging of c=0 immediately (lands under the preamble)
    {
        const short* src = bxg + (wave * 2) * 512 + lane * 8;
        gload_lds16(src,       &bxlds[0][(wave * 2) * 512]);
        gload_lds16(src + 512, &bxlds[0][(wave * 2 + 1) * 512]);
    }

    // ---- point features -> B-frags for both m-tiles (lane (q,l16) holds
    //      point l16's feature k = 8q+j — S1 k axis is identity)
    bf16x8 a0[2], a1[2];
#pragma unroll
    for (int m = 0; m < 2; ++m) {
        const float* pp = p + ((size_t)b * P + base + m * 16 + l16) * 3;
        float px = pp[0] - pos[b * 3 + 0];
        float py = pp[1] - pos[b * 3 + 1];
        float pz = pp[2] - pos[b * 3 + 2];
        float nrm = sqrtf(px * px + py * py + pz * pz);
        if (nrm > 0.5f) { float s = 0.5f / nrm; px *= s; py *= s; pz *= s; }
        float av[8];
        float s2 = 0.f;
#pragma unroll
        for (int j = 0; j < 8; ++j) {
            int k = quad * 8 + j;
            av[j] = px * W_feat[k] + py * W_feat[F + k] + pz * W_feat[2 * F + k];
            s2 += av[j] * av[j];
        }
        s2 += __shfl_xor(s2, 16);
        s2 += __shfl_xor(s2, 32);
        union { bf16x8 v; unsigned u[4]; } ua;
#pragma unroll
        for (int j = 0; j < 4; ++j) ua.u[j] = cvt_pk_bf16(av[2 * j], av[2 * j + 1]);
        a0[m] = ua.v;
        union { bf16x8 v; unsigned u[4]; } ub;
#pragma unroll
        for (int j = 0; j < 4; ++j) ub.u[j] = 0;
        if (quad == 0) ub.u[0] = cvt_pk_bf16(s2, 1.0f);
        a1[m] = ub.v;
    }

    f32x4 pooled[2][4];
#pragma unroll
    for (int m = 0; m < 2; ++m)
#pragma unroll
        for (int nt = 0; nt < 4; ++nt)
            pooled[m][nt] = (f32x4){-1e30f, -1e30f, -1e30f, -1e30f};

    // ---- biases in D-form: n = 16nt + 4q + r  ->  float4 at +16nt+4q
    float4 ba0v[4], bb0v[4];
#pragma unroll
    for (int nt = 0; nt < 4; ++nt) {
        ba0v[nt] = *(const float4*)(ba + nt * 16 + 4 * quad);
        bb0v[nt] = *(const float4*)(bb + nt * 16 + 4 * quad);
    }

    // ---- hoist layer-0 weight A-frags (c-invariant; 64 VGPRs)
    bf16x8 wa0f[4][2], wb0f[4][2];
#pragma unroll
    for (int nt = 0; nt < 4; ++nt) {
        wa0f[nt][0] = *(const bf16x8*)(Wat + (nt * 16 + l16) * 64 + quad * 8);
        wa0f[nt][1] = *(const bf16x8*)(Wat + (nt * 16 + l16) * 64 + 32 + quad * 8);
        wb0f[nt][0] = *(const bf16x8*)(Wbt + (nt * 16 + l16) * 64 + quad * 8);
        wb0f[nt][1] = *(const bf16x8*)(Wbt + (nt * 16 + l16) * 64 + 32 + quad * 8);
    }

    __syncthreads();   // drains vmcnt: bxlds[0] is published

    // =============== c-loop: 1 channel per iter, 2 m-chains =================
#pragma unroll 1
    for (int c = 0; c < C; ++c) {
        // ---- issue staging for c+1 (lands during S1-S3, sealed by barrier)
        if (c + 1 < C) {
            const short* src = bxg + (size_t)(c + 1) * 4096 + (wave * 2) * 512 + lane * 8;
            gload_lds16(src,       &bxlds[(c + 1) & 1][(wave * 2) * 512]);
            gload_lds16(src + 512, &bxlds[(c + 1) & 1][(wave * 2 + 1) * 512]);
        }
        const short* bxs = &bxlds[c & 1][0];

        // ---- S1: x[n, point] = mfma(A=Bxt rows, B=point-feat frag)
        f32x4 x[2][4];
#pragma unroll
        for (int nt = 0; nt < 4; ++nt) {
            const int row = nt * 16 + l16;
            const int sw  = (row & 7) << 3;
            bf16x8 b0f = *(const bf16x8*)(bxs + row * 64 + ((quad * 8) ^ sw));
            bf16x8 b1f = *(const bf16x8*)(bxs + row * 64 + ((32 + quad * 8) ^ sw));
#pragma unroll
            for (int m = 0; m < 2; ++m) {
                f32x4 acc = (f32x4){0.f, 0.f, 0.f, 0.f};
                acc = __builtin_amdgcn_mfma_f32_16x16x32_bf16(b0f, a0[m], acc, 0, 0, 0);
                acc = __builtin_amdgcn_mfma_f32_16x16x32_bf16(b1f, a1[m], acc, 0, 0, 0);
                x[m][nt] = acc;
            }
        }

        // ---- repack relu(x) -> B-frags (in-lane, zero shuffles)
        bf16x8 xf0[2], xf1[2];
#pragma unroll
        for (int m = 0; m < 2; ++m) repack_relu(x[m], xf0[m], xf1[m]);

        // ---- S2: h = relu(x) @ Wa0 + ba0   (D-form acc init from ba0v)
        f32x4 h[2][4];
#pragma unroll
        for (int nt = 0; nt < 4; ++nt) {
#pragma unroll
            for (int m = 0; m < 2; ++m) {
                f32x4 acc = (f32x4){ba0v[nt].x, ba0v[nt].y, ba0v[nt].z, ba0v[nt].w};
                acc = __builtin_amdgcn_mfma_f32_16x16x32_bf16(wa0f[nt][0], xf0[m], acc, 0, 0, 0);
                acc = __builtin_amdgcn_mfma_f32_16x16x32_bf16(wa0f[nt][1], xf1[m], acc, 0, 0, 0);
                h[m][nt] = acc;
            }
        }

        // ---- repack relu(h)
        bf16x8 hf0[2], hf1[2];
#pragma unroll
        for (int m = 0; m < 2; ++m) repack_relu(h[m], hf0[m], hf1[m]);

        // ---- S3: x + bb0 + relu(h) @ Wb0 ; max-pool over c
#pragma unroll
        for (int nt = 0; nt < 4; ++nt) {
#pragma unroll
            for (int m = 0; m < 2; ++m) {
                f32x4 acc = x[m][nt];
                acc[0] += bb0v[nt].x; acc[1] += bb0v[nt].y;
                acc[2] += bb0v[nt].z; acc[3] += bb0v[nt].w;
                acc = __builtin_amdgcn_mfma_f32_16x16x32_bf16(wb0f[nt][0], hf0[m], acc, 0, 0, 0);
                acc = __builtin_amdgcn_mfma_f32_16x16x32_bf16(wb0f[nt][1], hf1[m], acc, 0, 0, 0);
#pragma unroll
                for (int r = 0; r < 4; ++r)
                    pooled[m][nt][r] = fmaxf(pooled[m][nt][r], acc[r]);
            }
        }

        __syncthreads();   // publishes staged buffer; seals dbuf epochs
    }

    // =============== residual blocks 1..4 (2 chains: m-tiles) ===============
#pragma unroll
    for (int i = 1; i < 5; ++i) {
        const short* wa = Wat + i * 4096;
        const short* wb = Wbt + i * 4096;
        float4 bai[4], bbi[4];
#pragma unroll
        for (int nt = 0; nt < 4; ++nt) {
            bai[nt] = *(const float4*)(ba + i * H + nt * 16 + 4 * quad);
            bbi[nt] = *(const float4*)(bb + i * H + nt * 16 + 4 * quad);
        }

        bf16x8 pf0[2], pf1[2];
#pragma unroll
        for (int m = 0; m < 2; ++m) repack_relu(pooled[m], pf0[m], pf1[m]);

        f32x4 h[2][4];
#pragma unroll
        for (int nt = 0; nt < 4; ++nt) {
            bf16x8 w0f = *(const bf16x8*)(wa + (nt * 16 + l16) * 64 + quad * 8);
            bf16x8 w1f = *(const bf16x8*)(wa + (nt * 16 + l16) * 64 + 32 + quad * 8);
#pragma unroll
            for (int m = 0; m < 2; ++m) {
                f32x4 acc = (f32x4){bai[nt].x, bai[nt].y, bai[nt].z, bai[nt].w};
                acc = __builtin_amdgcn_mfma_f32_16x16x32_bf16(w0f, pf0[m], acc, 0, 0, 0);
                acc = __builtin_amdgcn_mfma_f32_16x16x32_bf16(w1f, pf1[m], acc, 0, 0, 0);
                h[m][nt] = acc;
            }
        }

        bf16x8 hf0[2], hf1[2];
#pragma unroll
        for (int m = 0; m < 2; ++m) repack_relu(h[m], hf0[m], hf1[m]);

#pragma unroll
        for (int nt = 0; nt < 4; ++nt) {
            bf16x8 w0f = *(const bf16x8*)(wb + (nt * 16 + l16) * 64 + quad * 8);
            bf16x8 w1f = *(const bf16x8*)(wb + (nt * 16 + l16) * 64 + 32 + quad * 8);
#pragma unroll
            for (int m = 0; m < 2; ++m) {
                f32x4 acc = pooled[m][nt];
                acc[0] += bbi[nt].x; acc[1] += bbi[nt].y;
                acc[2] += bbi[nt].z; acc[3] += bbi[nt].w;
                acc = __builtin_amdgcn_mfma_f32_16x16x32_bf16(w0f, hf0[m], acc, 0, 0, 0);
                acc = __builtin_amdgcn_mfma_f32_16x16x32_bf16(w1f, hf1[m], acc, 0, 0, 0);
                pooled[m][nt] = acc;
            }
        }
    }

    // =============== head: per-lane dot + cross-quad reduce =================
    const float bo = bout[0];
    float4 wo4[4];
#pragma unroll
    for (int nt = 0; nt < 4; ++nt)
        wo4[nt] = *(const float4*)(Wout + nt * 16 + 4 * quad);
#pragma unroll
    for (int m = 0; m < 2; ++m) {
        float s = 0.f;
#pragma unroll
        for (int nt = 0; nt < 4; ++nt) {
            s += fmaxf(pooled[m][nt][0], 0.f) * wo4[nt].x
               + fmaxf(pooled[m][nt][1], 0.f) * wo4[nt].y
               + fmaxf(pooled[m][nt][2], 0.f) * wo4[nt].z
               + fmaxf(pooled[m][nt][3], 0.f) * wo4[nt].w;
        }
        s += __shfl_xor(s, 16);
        s += __shfl_xor(s, 32);
        if (lane < 16)
            out[(size_t)b * P + base + m * 16 + l16] = s + bo;
    }
}

extern "C" void kernel_launch(void* const* d_in, const int* in_sizes, int n_in,
                              void* d_out, int out_size, void* d_ws, size_t ws_size,
                              hipStream_t stream) {
    const float* z      = (const float*)d_in[0];
    const float* pos    = (const float*)d_in[1];
    const float* p      = (const float*)d_in[2];
    const float* W_feat = (const float*)d_in[3];
    const float* W_dir  = (const float*)d_in[4];
    const float* W0     = (const float*)d_in[5];
    const float* b0     = (const float*)d_in[6];
    const float* Wa     = (const float*)d_in[7];
    const float* ba     = (const float*)d_in[8];
    const float* Wb     = (const float*)d_in[9];
    const float* bb     = (const float*)d_in[10];
    const float* Wout   = (const float*)d_in[11];
    const float* bout   = (const float*)d_in[12];
    float* out = (float*)d_out;

    short* wsS = (short*)d_ws;
    short* Bxt = wsS;                    // B*C*64*64 shorts
    short* Wat = wsS + 32 * 4096;        // 5*4096
    short* Wbt = Wat + 5 * 4096;         // 5*4096

    setup_kernel<<<112, 256, 0, stream>>>(z, W_dir, W0, b0, Wa, Wb, Bxt, Wat, Wbt);

    dim3 grid(P / 128, B);
    main_kernel<<<grid, 256, 0, stream>>>(p, pos, W_feat, Bxt, Wat, Wbt,
                                          ba, bb, Wout, bout, out);
}